// Round 1
// baseline (573.624 us; speedup 1.0000x reference)
//
#include <hip/hip_runtime.h>

#define NB 20000
#define EB 320000
#define BATCH 2
#define DIN 128
#define H1D 256
#define H2D 256
#define DOUTD 128

// ---------------------------------------------------------------------------
// Setup kernels: degree histogram -> exclusive scan (CSR row_start) -> scatter
// (counting sort of edges by dst). Avoids 327M float atomics in aggregation.
// ---------------------------------------------------------------------------

__global__ void zero_kernel(int* __restrict__ p, int n) {
    int t = blockIdx.x * blockDim.x + threadIdx.x;
    if (t < n) p[t] = 0;
}

__global__ void hist_kernel(const int* __restrict__ dst, int* __restrict__ counts) {
    int t = blockIdx.x * blockDim.x + threadIdx.x;
    if (t < EB) atomicAdd(&counts[dst[t]], 1);
}

// Single-block scan over N=20000 counts. Each of 1024 threads handles a
// 20-element chunk; Hillis-Steele over per-thread sums in LDS.
__global__ __launch_bounds__(1024) void scan_kernel(const int* __restrict__ counts,
                                                    int* __restrict__ row_start,
                                                    int* __restrict__ cursor,
                                                    float* __restrict__ dinv) {
    __shared__ int sums[1024];
    const int CH = (NB + 1023) / 1024;  // 20
    int t = threadIdx.x;
    int base = t * CH;
    int s = 0;
    for (int j = 0; j < CH; ++j) {
        int i = base + j;
        if (i < NB) s += counts[i];
    }
    sums[t] = s;
    __syncthreads();
    for (int off = 1; off < 1024; off <<= 1) {
        int v = (t >= off) ? sums[t - off] : 0;
        __syncthreads();
        sums[t] += v;
        __syncthreads();
    }
    int run = sums[t] - s;  // exclusive prefix for this chunk
    for (int j = 0; j < CH; ++j) {
        int i = base + j;
        if (i < NB) {
            row_start[i] = run;
            cursor[i] = run;
            int c = counts[i];
            run += c;
            // deg = in-degree + 1 (self loop)
            dinv[i] = rsqrtf((float)c + 1.0f);
        }
    }
    if (t == 1023) row_start[NB] = sums[1023];
}

__global__ void scatter_kernel(const int* __restrict__ src, const int* __restrict__ dst,
                               const float* __restrict__ dinv,
                               int* __restrict__ cursor,
                               int* __restrict__ src_sorted, float* __restrict__ w_sorted) {
    int t = blockIdx.x * blockDim.x + threadIdx.x;
    if (t < EB) {
        int d = dst[t], s = src[t];
        int p = atomicAdd(&cursor[d], 1);
        src_sorted[p] = s;
        w_sorted[p] = dinv[s] * dinv[d];
    }
}

// ---------------------------------------------------------------------------
// Aggregation: out[i,:] = sum_{e in CSR row i} h[src_e,:]*w_e + h[i,:]*dinv_i^2
//              (+ bias) (+ prelu). One block per node, one thread per feature.
// Gather reads are coalesced (full row per edge); writes coalesced; no atomics.
// ---------------------------------------------------------------------------
template <int F, bool BIAS, bool PRELU>
__global__ void agg_kernel(const float* __restrict__ h,
                           float* __restrict__ out,
                           const int* __restrict__ row_start,
                           const int* __restrict__ src_sorted,
                           const float* __restrict__ w_sorted,
                           const float* __restrict__ dinv,
                           const float* __restrict__ bias,
                           const float* __restrict__ pa) {
    int i = blockIdx.x;
    int f = threadIdx.x;
    float dv = dinv[i];
    float acc = h[(size_t)i * F + f] * (dv * dv);
    int e0 = row_start[i], e1 = row_start[i + 1];
    for (int e = e0; e < e1; ++e) {
        int s = src_sorted[e];     // block-uniform
        float w = w_sorted[e];     // block-uniform
        acc = fmaf(h[(size_t)s * F + f], w, acc);
    }
    if (BIAS) acc += bias[f];
    if (PRELU) {
        float a = *pa;
        acc = acc >= 0.0f ? acc : a * acc;
    }
    out[(size_t)i * F + f] = acc;
}

// ---------------------------------------------------------------------------
// FP32 GEMM: C[M,Nc] = A[M,K] @ W[K,Nc] (+bias) (+prelu).
// 64x64 block tile, BK=16, 256 threads, 4x4 per-thread microtile.
// ---------------------------------------------------------------------------
template <bool BIAS, bool PRELU>
__global__ __launch_bounds__(256) void gemm_kernel(const float* __restrict__ A, int M, int K,
                                                   const float* __restrict__ W, int Nc,
                                                   const float* __restrict__ bias,
                                                   const float* __restrict__ pa,
                                                   float* __restrict__ C) {
    __shared__ alignas(16) float As[16][68];  // transposed: As[k][m], pad 68 (272B rows, 16B-aligned)
    __shared__ alignas(16) float Bs[16][68];  // Bs[k][n]
    int t = threadIdx.x;
    int bm = blockIdx.x * 64;
    int bn = blockIdx.y * 64;
    int tx = t & 15, ty = t >> 4;
    int m0 = ty * 4, n0 = tx * 4;
    // A-tile staging: thread t loads float4 at (row=t>>2, col4=t&3)
    int ar = t >> 2, ac4 = (t & 3) * 4;
    // B-tile staging: thread t loads float4 at (row=t>>4, col4=t&15)
    int br = t >> 4, bc4 = (t & 15) * 4;

    float acc[4][4] = {};

    for (int k0 = 0; k0 < K; k0 += 16) {
        float4 av = make_float4(0.f, 0.f, 0.f, 0.f);
        int arow = bm + ar;
        if (arow < M) av = *(const float4*)&A[(size_t)arow * K + k0 + ac4];
        As[ac4 + 0][ar] = av.x;
        As[ac4 + 1][ar] = av.y;
        As[ac4 + 2][ar] = av.z;
        As[ac4 + 3][ar] = av.w;
        float4 bv = *(const float4*)&W[(size_t)(k0 + br) * Nc + bn + bc4];
        *(float4*)&Bs[br][bc4] = bv;
        __syncthreads();
#pragma unroll
        for (int k = 0; k < 16; ++k) {
            float4 av4 = *(const float4*)&As[k][m0];
            float4 bv4 = *(const float4*)&Bs[k][n0];
            float a_[4] = {av4.x, av4.y, av4.z, av4.w};
            float b_[4] = {bv4.x, bv4.y, bv4.z, bv4.w};
#pragma unroll
            for (int i = 0; i < 4; ++i)
#pragma unroll
                for (int j = 0; j < 4; ++j)
                    acc[i][j] = fmaf(a_[i], b_[j], acc[i][j]);
        }
        __syncthreads();
    }

    float pav = 0.0f;
    if (PRELU) pav = *pa;
#pragma unroll
    for (int i = 0; i < 4; ++i) {
        int row = bm + m0 + i;
        if (row < M) {
            float v[4];
#pragma unroll
            for (int j = 0; j < 4; ++j) {
                float x = acc[i][j];
                if (BIAS) x += bias[bn + n0 + j];
                if (PRELU) x = (x >= 0.0f) ? x : pav * x;
                v[j] = x;
            }
            *(float4*)&C[(size_t)row * Nc + bn + n0] = make_float4(v[0], v[1], v[2], v[3]);
        }
    }
}

// ---------------------------------------------------------------------------

static inline char* carve(char*& p, size_t bytes) {
    char* r = p;
    p += (bytes + 255) & ~(size_t)255;
    return r;
}

extern "C" void kernel_launch(void* const* d_in, const int* in_sizes, int n_in,
                              void* d_out, int out_size, void* d_ws, size_t ws_size,
                              hipStream_t stream) {
    const float* X  = (const float*)d_in[0];
    const float* W1 = (const float*)d_in[1];
    const float* b1 = (const float*)d_in[2];
    const float* W2 = (const float*)d_in[3];
    const float* b2 = (const float*)d_in[4];
    const float* W3 = (const float*)d_in[5];
    const float* b3 = (const float*)d_in[6];
    const float* pa = (const float*)d_in[7];
    const int* ei   = (const int*)d_in[8];
    const int* src = ei;
    const int* dst = ei + EB;
    float* out = (float*)d_out;

    char* p = (char*)d_ws;
    int* counts      = (int*)carve(p, NB * sizeof(int));
    int* row_start   = (int*)carve(p, (NB + 1) * sizeof(int));
    int* cursor      = (int*)carve(p, NB * sizeof(int));
    int* src_sorted  = (int*)carve(p, EB * sizeof(int));
    float* w_sorted  = (float*)carve(p, EB * sizeof(float));
    float* dinv      = (float*)carve(p, NB * sizeof(float));
    float* bufA      = (float*)carve(p, (size_t)NB * 256 * sizeof(float));
    float* bufB      = (float*)carve(p, (size_t)NB * 256 * sizeof(float));

    // --- CSR build (once per call, reused by all 6 aggregations) ---
    zero_kernel<<<(NB + 255) / 256, 256, 0, stream>>>(counts, NB);
    hist_kernel<<<(EB + 255) / 256, 256, 0, stream>>>(dst, counts);
    scan_kernel<<<1, 1024, 0, stream>>>(counts, row_start, cursor, dinv);
    scatter_kernel<<<(EB + 255) / 256, 256, 0, stream>>>(src, dst, dinv, cursor,
                                                         src_sorted, w_sorted);

    for (int b = 0; b < BATCH; ++b) {
        const float* Xb = X + (size_t)b * NB * DIN;
        float* outb = out + (size_t)b * NB * DOUTD;

        // Layer 1: aggregate X first (F=128), then GEMM(+b1,+prelu).
        agg_kernel<128, false, false><<<NB, 128, 0, stream>>>(
            Xb, bufA, row_start, src_sorted, w_sorted, dinv, nullptr, nullptr);
        gemm_kernel<true, true><<<dim3((NB + 63) / 64, 256 / 64), 256, 0, stream>>>(
            bufA, NB, 128, W1, 256, b1, pa, bufB);

        // Layer 2: GEMM then aggregate (+b2,+prelu).
        gemm_kernel<false, false><<<dim3((NB + 63) / 64, 256 / 64), 256, 0, stream>>>(
            bufB, NB, 256, W2, 256, nullptr, nullptr, bufA);
        agg_kernel<256, true, true><<<NB, 256, 0, stream>>>(
            bufA, bufB, row_start, src_sorted, w_sorted, dinv, b2, pa);

        // Layer 3: GEMM then aggregate (+b3, no prelu) -> output.
        gemm_kernel<false, false><<<dim3((NB + 63) / 64, 128 / 64), 256, 0, stream>>>(
            bufB, NB, 256, W3, 128, nullptr, nullptr, bufA);
        agg_kernel<128, true, false><<<NB, 128, 0, stream>>>(
            bufA, outb, row_start, src_sorted, w_sorted, dinv, b3, nullptr);
    }
}

// Round 2
// 414.699 us; speedup vs baseline: 1.3832x; 1.3832x over previous
//
#include <hip/hip_runtime.h>

#define NB 20000
#define EB 320000
#define DIN 128
#define H1D 256
#define H2D 256
#define DOUTD 128

// ---------------------------------------------------------------------------
// Setup: degree histogram -> scan (CSR row_start + dinv) -> counting-sort
// scatter of edges into int2{src, w_bits} records. ~1M int atomics total,
// reused by all aggregations.
// ---------------------------------------------------------------------------

__global__ void zero_kernel(int* __restrict__ p, int n) {
    int t = blockIdx.x * blockDim.x + threadIdx.x;
    if (t < n) p[t] = 0;
}

__global__ void hist_kernel(const int* __restrict__ dst, int* __restrict__ counts) {
    int t = blockIdx.x * blockDim.x + threadIdx.x;
    if (t < EB) atomicAdd(&counts[dst[t]], 1);
}

__global__ __launch_bounds__(1024) void scan_kernel(const int* __restrict__ counts,
                                                    int* __restrict__ row_start,
                                                    int* __restrict__ cursor,
                                                    float* __restrict__ dinv) {
    __shared__ int sums[1024];
    const int CH = (NB + 1023) / 1024;  // 20
    int t = threadIdx.x;
    int base = t * CH;
    int s = 0;
    for (int j = 0; j < CH; ++j) {
        int i = base + j;
        if (i < NB) s += counts[i];
    }
    sums[t] = s;
    __syncthreads();
    for (int off = 1; off < 1024; off <<= 1) {
        int v = (t >= off) ? sums[t - off] : 0;
        __syncthreads();
        sums[t] += v;
        __syncthreads();
    }
    int run = sums[t] - s;  // exclusive prefix of this chunk
    for (int j = 0; j < CH; ++j) {
        int i = base + j;
        if (i < NB) {
            row_start[i] = run;
            cursor[i] = run;
            int c = counts[i];
            run += c;
            dinv[i] = rsqrtf((float)c + 1.0f);  // deg = in-degree + 1 (self loop)
        }
    }
    if (t == 1023) row_start[NB] = sums[1023];
}

__global__ void scatter_kernel(const int* __restrict__ src, const int* __restrict__ dst,
                               const float* __restrict__ dinv,
                               int* __restrict__ cursor, int2* __restrict__ edges) {
    int t = blockIdx.x * blockDim.x + threadIdx.x;
    if (t < EB) {
        int d = dst[t], s = src[t];
        int p = atomicAdd(&cursor[d], 1);
        edges[p] = make_int2(s, __float_as_int(dinv[s] * dinv[d]));
    }
}

// ---------------------------------------------------------------------------
// Aggregation: one WAVE per node; lane handles F/64 contiguous floats.
// Edge loop unrolled x4 with 4 independent accumulators -> 4 loads in flight
// (MLP=4) instead of a serial load->fma chain. Edge records are one 8B load.
// ---------------------------------------------------------------------------

__device__ inline void vload(float (&d)[4], const float* p) {
    float4 t = *(const float4*)p; d[0] = t.x; d[1] = t.y; d[2] = t.z; d[3] = t.w;
}
__device__ inline void vload(float (&d)[2], const float* p) {
    float2 t = *(const float2*)p; d[0] = t.x; d[1] = t.y;
}
__device__ inline void vstore(float* p, const float (&d)[4]) {
    *(float4*)p = make_float4(d[0], d[1], d[2], d[3]);
}
__device__ inline void vstore(float* p, const float (&d)[2]) {
    *(float2*)p = make_float2(d[0], d[1]);
}

template <int F, bool BIAS, bool PRELU>
__global__ __launch_bounds__(256) void agg_kernel(
    const float* __restrict__ h, float* __restrict__ out,
    const int* __restrict__ row_start, const int2* __restrict__ edges,
    const float* __restrict__ dinv, const float* __restrict__ bias,
    const float* __restrict__ pa, int nnodes) {
    constexpr int VEC = F / 64;
    int wid = threadIdx.x >> 6;
    int lane = threadIdx.x & 63;
    int g = blockIdx.x * 4 + wid;            // global row (batch-fused index)
    if (g >= nnodes) return;
    int icsr = g;
    int hbase = 0;
    if (icsr >= NB) { icsr -= NB; hbase = NB; }  // batch 1 rows live at +NB
    const float* hsrc = h + (size_t)hbase * F + (size_t)lane * VEC;
    const float* hown = h + (size_t)g * F + (size_t)lane * VEC;

    float acc0[VEC], acc1[VEC] = {}, acc2[VEC] = {}, acc3[VEC] = {};
    float dv = dinv[icsr];
    float sw = dv * dv;
    {
        float t[VEC];
        vload(t, hown);
#pragma unroll
        for (int v = 0; v < VEC; ++v) acc0[v] = t[v] * sw;
    }
    int e0 = __builtin_amdgcn_readfirstlane(row_start[icsr]);
    int e1 = __builtin_amdgcn_readfirstlane(row_start[icsr + 1]);
    int e = e0;
    for (; e + 4 <= e1; e += 4) {
        int2 ed0 = edges[e], ed1 = edges[e + 1], ed2 = edges[e + 2], ed3 = edges[e + 3];
        float t0[VEC], t1[VEC], t2[VEC], t3[VEC];
        vload(t0, hsrc + (size_t)ed0.x * F);
        vload(t1, hsrc + (size_t)ed1.x * F);
        vload(t2, hsrc + (size_t)ed2.x * F);
        vload(t3, hsrc + (size_t)ed3.x * F);
        float w0 = __int_as_float(ed0.y), w1 = __int_as_float(ed1.y);
        float w2 = __int_as_float(ed2.y), w3 = __int_as_float(ed3.y);
#pragma unroll
        for (int v = 0; v < VEC; ++v) {
            acc0[v] = fmaf(t0[v], w0, acc0[v]);
            acc1[v] = fmaf(t1[v], w1, acc1[v]);
            acc2[v] = fmaf(t2[v], w2, acc2[v]);
            acc3[v] = fmaf(t3[v], w3, acc3[v]);
        }
    }
    for (; e < e1; ++e) {
        int2 ed = edges[e];
        float t[VEC];
        vload(t, hsrc + (size_t)ed.x * F);
        float w = __int_as_float(ed.y);
#pragma unroll
        for (int v = 0; v < VEC; ++v) acc0[v] = fmaf(t[v], w, acc0[v]);
    }
#pragma unroll
    for (int v = 0; v < VEC; ++v) acc0[v] += (acc1[v] + acc2[v]) + acc3[v];
    if (BIAS) {
        float bv[VEC];
        vload(bv, bias + lane * VEC);
#pragma unroll
        for (int v = 0; v < VEC; ++v) acc0[v] += bv[v];
    }
    if (PRELU) {
        float a = *pa;
#pragma unroll
        for (int v = 0; v < VEC; ++v) acc0[v] = acc0[v] >= 0.0f ? acc0[v] : a * acc0[v];
    }
    vstore(out + (size_t)g * F + lane * VEC, acc0);
}

// ---------------------------------------------------------------------------
// FP32 GEMM: C[M,Nc] = A[M,K] @ W[K,Nc] (+bias) (+prelu).
// 64x64 tile, BK=16, 256 threads, 4x4 microtile. VALU-bound (no fp32 MFMA).
// ---------------------------------------------------------------------------
template <bool BIAS, bool PRELU>
__global__ __launch_bounds__(256) void gemm_kernel(const float* __restrict__ A, int M, int K,
                                                   const float* __restrict__ W, int Nc,
                                                   const float* __restrict__ bias,
                                                   const float* __restrict__ pa,
                                                   float* __restrict__ C) {
    __shared__ alignas(16) float As[16][68];
    __shared__ alignas(16) float Bs[16][68];
    int t = threadIdx.x;
    int bm = blockIdx.x * 64;
    int bn = blockIdx.y * 64;
    int tx = t & 15, ty = t >> 4;
    int m0 = ty * 4, n0 = tx * 4;
    int ar = t >> 2, ac4 = (t & 3) * 4;
    int br = t >> 4, bc4 = (t & 15) * 4;

    float acc[4][4] = {};

    for (int k0 = 0; k0 < K; k0 += 16) {
        float4 av = make_float4(0.f, 0.f, 0.f, 0.f);
        int arow = bm + ar;
        if (arow < M) av = *(const float4*)&A[(size_t)arow * K + k0 + ac4];
        As[ac4 + 0][ar] = av.x;
        As[ac4 + 1][ar] = av.y;
        As[ac4 + 2][ar] = av.z;
        As[ac4 + 3][ar] = av.w;
        float4 bv = *(const float4*)&W[(size_t)(k0 + br) * Nc + bn + bc4];
        *(float4*)&Bs[br][bc4] = bv;
        __syncthreads();
#pragma unroll
        for (int k = 0; k < 16; ++k) {
            float4 av4 = *(const float4*)&As[k][m0];
            float4 bv4 = *(const float4*)&Bs[k][n0];
            float a_[4] = {av4.x, av4.y, av4.z, av4.w};
            float b_[4] = {bv4.x, bv4.y, bv4.z, bv4.w};
#pragma unroll
            for (int i = 0; i < 4; ++i)
#pragma unroll
                for (int j = 0; j < 4; ++j)
                    acc[i][j] = fmaf(a_[i], b_[j], acc[i][j]);
        }
        __syncthreads();
    }

    float pav = 0.0f;
    if (PRELU) pav = *pa;
#pragma unroll
    for (int i = 0; i < 4; ++i) {
        int row = bm + m0 + i;
        if (row < M) {
            float v[4];
#pragma unroll
            for (int j = 0; j < 4; ++j) {
                float x = acc[i][j];
                if (BIAS) x += bias[bn + n0 + j];
                if (PRELU) x = (x >= 0.0f) ? x : pav * x;
                v[j] = x;
            }
            *(float4*)&C[(size_t)row * Nc + bn + n0] = make_float4(v[0], v[1], v[2], v[3]);
        }
    }
}

// ---------------------------------------------------------------------------

static inline char* carve(char*& p, size_t bytes) {
    char* r = p;
    p += (bytes + 255) & ~(size_t)255;
    return r;
}

extern "C" void kernel_launch(void* const* d_in, const int* in_sizes, int n_in,
                              void* d_out, int out_size, void* d_ws, size_t ws_size,
                              hipStream_t stream) {
    const float* X  = (const float*)d_in[0];
    const float* W1 = (const float*)d_in[1];
    const float* b1 = (const float*)d_in[2];
    const float* W2 = (const float*)d_in[3];
    const float* b2 = (const float*)d_in[4];
    const float* W3 = (const float*)d_in[5];
    const float* b3 = (const float*)d_in[6];
    const float* pa = (const float*)d_in[7];
    const int* ei   = (const int*)d_in[8];
    const int* src = ei;
    const int* dst = ei + EB;
    float* out = (float*)d_out;

    // Fixed-size small allocations
    char* p = (char*)d_ws;
    int* counts    = (int*)carve(p, NB * sizeof(int));
    int* row_start = (int*)carve(p, (NB + 1) * sizeof(int));
    int* cursor    = (int*)carve(p, NB * sizeof(int));
    int2* edges    = (int2*)carve(p, EB * sizeof(int2));
    float* dinv    = (float*)carve(p, NB * sizeof(float));

    // Decide fused (both batches in one M=40000 pass) vs per-batch by ws room.
    size_t fixed = (size_t)(p - (char*)d_ws);
    size_t need_fused = fixed + 2 * ((size_t)2 * NB * 256 * sizeof(float) + 256);
    bool fused = ws_size >= need_fused;
    size_t rows = fused ? 2 * NB : NB;
    float* bufA = (float*)carve(p, rows * 256 * sizeof(float));
    float* bufB = (float*)carve(p, rows * 256 * sizeof(float));

    // --- CSR build (once, reused by all aggregations) ---
    zero_kernel<<<(NB + 255) / 256, 256, 0, stream>>>(counts, NB);
    hist_kernel<<<(EB + 255) / 256, 256, 0, stream>>>(dst, counts);
    scan_kernel<<<1, 1024, 0, stream>>>(counts, row_start, cursor, dinv);
    scatter_kernel<<<(EB + 255) / 256, 256, 0, stream>>>(src, dst, dinv, cursor, edges);

    int nbatch_loops = fused ? 1 : 2;
    for (int b = 0; b < nbatch_loops; ++b) {
        const float* Xb = X + (size_t)b * NB * DIN;
        float* outb = out + (size_t)b * NB * DOUTD;
        int M = (int)rows;
        int aggGrid = (M + 3) / 4;

        // Layer 1: aggregate X first (F=128), then GEMM(+b1,+prelu).
        agg_kernel<128, false, false><<<aggGrid, 256, 0, stream>>>(
            Xb, bufA, row_start, edges, dinv, nullptr, nullptr, M);
        gemm_kernel<true, true><<<dim3((M + 63) / 64, H1D / 64), 256, 0, stream>>>(
            bufA, M, DIN, W1, H1D, b1, pa, bufB);

        // Layer 2: GEMM then aggregate (+b2,+prelu).
        gemm_kernel<false, false><<<dim3((M + 63) / 64, H2D / 64), 256, 0, stream>>>(
            bufB, M, H1D, W2, H2D, nullptr, nullptr, bufA);
        agg_kernel<256, true, true><<<aggGrid, 256, 0, stream>>>(
            bufA, bufB, row_start, edges, dinv, b2, pa, M);

        // Layer 3: GEMM then aggregate (+b3, no prelu) -> output.
        gemm_kernel<false, false><<<dim3((M + 63) / 64, DOUTD / 64), 256, 0, stream>>>(
            bufB, M, H2D, W3, DOUTD, nullptr, nullptr, bufA);
        agg_kernel<128, true, false><<<aggGrid, 256, 0, stream>>>(
            bufA, outb, row_start, edges, dinv, b3, nullptr, M);
    }
}